// Round 7
// baseline (126.760 us; speedup 1.0000x reference)
//
#include <hip/hip_runtime.h>
#include <hip/hip_bf16.h>

namespace {

constexpr float kAlpha = 0.025f;
constexpr float kC1 = 1.0e-4f;  // (0.01*1)^2
constexpr float kC2 = 9.0e-4f;  // (0.03*1)^2

constexpr int MPS = 72;   // patch row stride (shorts): 144 B, 16B-aligned
constexpr int HTS = 104;  // hbT per-outcol stride (shorts): 208 B, 16B-aligned
constexpr int PRW = 96;   // patch rows

typedef __attribute__((ext_vector_type(8))) short short8;
typedef __attribute__((ext_vector_type(4))) float f32x4;

// r7: 64x32-output tiles, 512 threads (8 waves), 2048 blocks. Halo work per
// output: patch 3x (vs 4x), H-conv 1.5x (vs 2x), barriers/output halved;
// V-pass unchanged. H: wave = (map w&3, row-group w>>2) -> A[3][2] (24 regs).
// V: wave = out tile (rt=w>>1, ct=w&1), K-tile base kb=rt>>1 (each 16-row
// out tile spans exactly 2 of the 3 H-row K-tiles).
// LDS: union(mp 27648, hbT 26624) + red 32 + gtab 1920 = 29600 B.
struct __align__(16) Smem {
  union {
    short mp[2][PRW * MPS];  // bf16 pixel maps: x, y (staging only)
    short hbT[4][32 * HTS];  // bf16 H results, transposed [out_col][row]
  };
  float red[8];
  // tap tables: entry e[t] = bf16(g[t-31]) for t-31 in [0,32], else 0.
  // gtab[0][s][i] = (e[2i], e[2i+1]); gtab[1][s][i] = (e[2i+1], e[2i+2])
  int gtab[2][5][48];
};

union Frag {
  int i[4];
  int4 i4;
  short8 s8;
};

__device__ __forceinline__ unsigned f2bf(float f) {  // RNE fp32 -> bf16 bits
  unsigned u = __float_as_uint(f);
  return (u + 0x7FFFu + ((u >> 16) & 1u)) >> 16;
}
__device__ __forceinline__ unsigned pk(float a, float b) {  // v_cvt_pk_bf16
  union {
    __hip_bfloat162 h;
    unsigned u;
  } c;
  c.h = __float22bfloat162_rn(make_float2(a, b));
  return c.u;
}
__device__ __forceinline__ float bfl(unsigned u) {
  return __uint_as_float(u << 16);
}
__device__ __forceinline__ float bfh(unsigned u) {
  return __uint_as_float(u & 0xFFFF0000u);
}
__device__ __forceinline__ float frcp(float x) {  // v_rcp_f32, ~1 ulp
  return __builtin_amdgcn_rcpf(x);
}

// W fragment from the parity table: element j of (nt,kt) = g[k-n],
// k = kt*32 + quad*8 + j, n = nt*16 + l16. Start parity is lane-only, so
// per-lane table base is fixed; fragment = 4 consecutive dwords at
// tb[16kt - 8nt + 8 + j]. Used for H (nt=out col tile, kt=0,1) and V
// (nt=rt out row tile 0..3, kt=kb,kb+1 with kb=rt>>1).
__device__ __forceinline__ short8 wbuild2(const int* tb, int nt, int kt) {
  Frag u;
#pragma unroll
  for (int j = 0; j < 4; ++j) u.i[j] = tb[16 * kt - 8 * nt + 8 + j];
  return u.s8;
}

__device__ __forceinline__ void load_xy(const Smem& sm, int row, int quad,
                                        Frag fx[2], Frag fy[2]) {
  const short* px = &sm.mp[0][row * MPS + quad * 8];
  const short* py = &sm.mp[1][row * MPS + quad * 8];
  fx[0].i4 = *(const int4*)(px);       // 16B-aligned
  fx[1].i4 = *(const int4*)(px + 32);  // +64 B
  fy[0].i4 = *(const int4*)(py);
  fy[1].i4 = *(const int4*)(py + 32);
}

template <bool USE_WS>
__global__ __launch_bounds__(512, 4) void msssim_l1_kernel(
    const float* __restrict__ x, const float* __restrict__ y,
    const float* __restrict__ gm, float* __restrict__ partial,
    float* __restrict__ out) {
  __shared__ Smem sm;
  const int tid = threadIdx.x;
  const int lane = tid & 63;
  const int w = tid >> 6;   // 0..7
  const int quad = lane >> 4;
  const int l16 = lane & 15;
  const int wmap = w & 3;   // H: which map this wave convolves
  const int wgrp = w >> 2;  // H: row-group (mtiles 3*wgrp..3*wgrp+2)
  const int rt = w >> 1;    // V: out row tile 0..3
  const int ct = w & 1;     // V: out col tile 0..1
  const int kb = rt >> 1;   // V: K-tile base (0 for rt<2, 1 for rt>=2)
  const int l1i = w & 3;    // l1: index of this wave's mtile in its group
  const bool l1on = l1i < 3;
  const f32x4 kZ = {0.f, 0.f, 0.f, 0.f};

  // corr: fp32/bf16 tap-sum compensation for the l1 conv (sigma 4)
  float corr;
  {
    float traw4 = (lane < 33) ? gm[4 * 1089 + 528 + lane] : 0.f;
    float g = traw4 * rsqrtf(__shfl(traw4, 16, 64));
    float se = g, st = bfl(f2bf(g));
#pragma unroll
    for (int off = 32; off > 0; off >>= 1) {
      se += __shfl_xor(se, off, 64);
      st += __shfl_xor(st, off, 64);
    }
    float r1 = se / st;
    corr = r1 * r1;
  }

  // build dual-parity tap tables (480 dwords; gm is L2-hot)
  if (tid < 480) {
    int* gt = &sm.gtab[0][0][0];
    int q = tid;
    int par = q >= 240;
    int rem = par ? q - 240 : q;
    int s = rem / 48;
    int i = rem - s * 48;
    int t0 = 2 * i + par;
    const float* grow = gm + s * 1089 + 528;
    float rsc = rsqrtf(grow[16]);
    int g0 = t0 - 31, g1 = t0 - 30;
    unsigned lo = (g0 >= 0 && g0 <= 32) ? f2bf(grow[g0] * rsc) : 0u;
    unsigned hi = (g1 >= 0 && g1 <= 32) ? f2bf(grow[g1] * rsc) : 0u;
    gt[q] = (int)(lo | (hi << 16));
  }

  // per-lane table base: parity of start = (l16+1)&1; bias -8 keeps all
  // wbuild2 immediate offsets non-negative
  const int D = (quad * 8 - l16 + 31) >> 1;
  const int* gD = &sm.gtab[(l16 & 1) ? 0 : 1][0][0] + D - 8;

  // 96x64 halo patch, zero-padded; bf16 x/y maps in LDS (mp region)
  const float* xb = x + blockIdx.z * (512 * 512);
  const float* yb = y + blockIdx.z * (512 * 512);
  const int rb = blockIdx.y * 64 - 16;
  const int cb = blockIdx.x * 32 - 16;
  for (int f = tid; f < 1536; f += 512) {
    int pr = f >> 4;
    int pc = (f & 15) << 2;
    int gr = rb + pr, gc = cb + pc;
    float4 vx = make_float4(0.f, 0.f, 0.f, 0.f);
    float4 vy = vx;
    if (gr >= 0 && gr < 512 && gc >= 0 && gc < 512) {
      vx = *(const float4*)(xb + gr * 512 + gc);
      vy = *(const float4*)(yb + gr * 512 + gc);
    }
    const int base = pr * MPS + pc;
    *(int2*)(&sm.mp[0][base]) =
        make_int2((int)pk(vx.x, vx.y), (int)pk(vx.z, vx.w));
    *(int2*)(&sm.mp[1][base]) =
        make_int2((int)pk(vy.x, vy.y), (int)pk(vy.z, vy.w));
  }
  __syncthreads();  // B1: patch + tables ready

  // persistent A-fragments: wave convolves map wmap over its 3 mtiles;
  // 6 of 8 waves also build |x-y| fragments for one mtile (l1 plane)
  Frag A[3][2];
  Frag dA[2];
  dA[0].i4 = make_int4(0, 0, 0, 0);
  dA[1].i4 = make_int4(0, 0, 0, 0);
#pragma unroll
  for (int i = 0; i < 3; ++i) {
    const int mt = 3 * wgrp + i;
    Frag fx[2], fy[2];
    load_xy(sm, mt * 16 + l16, quad, fx, fy);
    if (l1on && i == l1i) {  // own-mtile |x-y| fragments (l1 plane)
#pragma unroll
      for (int h = 0; h < 2; ++h)
#pragma unroll
        for (int j = 0; j < 4; ++j) {
          unsigned ux = (unsigned)fx[h].i[j], uy = (unsigned)fy[h].i[j];
          dA[h].i[j] =
              (int)pk(fabsf(bfl(ux) - bfl(uy)), fabsf(bfh(ux) - bfh(uy)));
        }
    }
    if (wmap == 0) {
      A[i][0] = fx[0];
      A[i][1] = fx[1];
    } else if (wmap == 1) {
      A[i][0] = fy[0];
      A[i][1] = fy[1];
    } else {
#pragma unroll
      for (int h = 0; h < 2; ++h)
#pragma unroll
        for (int j = 0; j < 4; ++j) {
          unsigned ux = (unsigned)fx[h].i[j], uy = (unsigned)fy[h].i[j];
          float xl = bfl(ux), xh = bfh(ux), yl = bfl(uy), yh = bfh(uy);
          A[i][h].i[j] = (wmap == 2) ? (int)pk(fmaf(xl, xl, yl * yl),
                                              fmaf(xh, xh, yh * yh))
                                     : (int)pk(xl * yl, xh * yh);
        }
    }
  }

  // l1 H-pass HOISTED: result held packed in 4 regs until the tail
  int2 l1h[2] = {make_int2(0, 0), make_int2(0, 0)};
  if (l1on) {
    const int* tb = gD + 4 * 48;
#pragma unroll
    for (int nt = 0; nt < 2; ++nt) {
      short8 w0 = wbuild2(tb, nt, 0);
      short8 w1 = wbuild2(tb, nt, 1);
      f32x4 acc = __builtin_amdgcn_mfma_f32_16x16x32_bf16(dA[0].s8, w0, kZ, 0,
                                                          0, 0);
      acc = __builtin_amdgcn_mfma_f32_16x16x32_bf16(dA[1].s8, w1, acc, 0, 0,
                                                    0);
      l1h[nt] = make_int2((int)pk(acc[0], acc[1]), (int)pk(acc[2], acc[3]));
    }
  }
  __syncthreads();  // B2: all mp reads done -> hbT may overwrite the union

  f32x4 Pcs = {1.f, 1.f, 1.f, 1.f};
  f32x4 lumP = {0.f, 0.f, 0.f, 0.f};
  f32x4 l1v = {0.f, 0.f, 0.f, 0.f};

  // ============== one sigma per barrier pair: 4 planes in hbT ==============
#pragma unroll
  for (int s = 0; s < 5; ++s) {
    const int* tb = gD + s * 48;
    // H pass: wave (wmap, wgrp) -> hbT plane wmap, rows 48*wgrp..48*wgrp+47
#pragma unroll
    for (int nt = 0; nt < 2; ++nt) {
      short8 w0 = wbuild2(tb, nt, 0);
      short8 w1 = wbuild2(tb, nt, 1);
#pragma unroll
      for (int i = 0; i < 3; ++i) {
        const int mt = 3 * wgrp + i;
        f32x4 acc = __builtin_amdgcn_mfma_f32_16x16x32_bf16(A[i][0].s8, w0,
                                                            kZ, 0, 0, 0);
        acc = __builtin_amdgcn_mfma_f32_16x16x32_bf16(A[i][1].s8, w1, acc, 0,
                                                      0, 0);
        *(int2*)(&sm.hbT[wmap][(nt * 16 + l16) * HTS + mt * 16 + quad * 4]) =
            make_int2((int)pk(acc[0], acc[1]), (int)pk(acc[2], acc[3]));
      }
    }
    __syncthreads();  // sigma-s hbT ready

    // V pass + combine: wave = out tile (rt, ct), K-tiles kb, kb+1
    short8 wa0 = wbuild2(tb, rt, kb);
    short8 wa1 = wbuild2(tb, rt, kb + 1);
    f32x4 mux, muy, T;
#pragma unroll
    for (int m = 0; m < 4; ++m) {
      const short* bp = &sm.hbT[m][(ct * 16 + l16) * HTS + kb * 32 + quad * 8];
      Frag b0, b1;
      b0.i4 = *(const int4*)(bp);       // 16B-aligned
      b1.i4 = *(const int4*)(bp + 32);  // +64 B
      f32x4 acc =
          __builtin_amdgcn_mfma_f32_16x16x32_bf16(wa0, b0.s8, kZ, 0, 0, 0);
      acc = __builtin_amdgcn_mfma_f32_16x16x32_bf16(wa1, b1.s8, acc, 0, 0, 0);
      if (m == 0) {
        mux = acc;
      } else if (m == 1) {
        muy = acc;
      } else if (m == 2) {
#pragma unroll
        for (int r = 0; r < 4; ++r)
          T[r] = (acc[r] - mux[r] * mux[r]) - muy[r] * muy[r];
      } else {
#pragma unroll
        for (int r = 0; r < 4; ++r) {
          float cs =
              (2.f * (acc[r] - mux[r] * muy[r]) + kC2) * frcp(T[r] + kC2);
          Pcs[r] *= cs;
          if (s == 4)
            lumP[r] = ((2.f * (mux[r] * muy[r]) + kC1) *
                       frcp((mux[r] * mux[r] + muy[r] * muy[r]) + kC1)) *
                      Pcs[r];
        }
      }
    }
    __syncthreads();  // V reads done, hbT reusable
  }

  // ============ l1 plane tail: write hoisted H result, V-pass ============
  {
    const int* tb = gD + 4 * 48;
    if (l1on) {
#pragma unroll
      for (int nt = 0; nt < 2; ++nt)
        *(int2*)(&sm.hbT[0][(nt * 16 + l16) * HTS + (3 * wgrp + l1i) * 16 +
                            quad * 4]) = l1h[nt];
    }
    __syncthreads();  // l1 hbT ready

    short8 wa0 = wbuild2(tb, rt, kb);
    short8 wa1 = wbuild2(tb, rt, kb + 1);
    const short* bp = &sm.hbT[0][(ct * 16 + l16) * HTS + kb * 32 + quad * 8];
    Frag b0, b1;
    b0.i4 = *(const int4*)(bp);
    b1.i4 = *(const int4*)(bp + 32);
    f32x4 acc =
        __builtin_amdgcn_mfma_f32_16x16x32_bf16(wa0, b0.s8, kZ, 0, 0, 0);
    acc = __builtin_amdgcn_mfma_f32_16x16x32_bf16(wa1, b1.s8, acc, 0, 0, 0);
#pragma unroll
    for (int r = 0; r < 4; ++r) l1v[r] = acc[r] * corr;
  }

  // loss_mix = alpha*(1 - lum*PIcs) + (1-alpha)*gaussian_l1
  float lsum = 0.f;
#pragma unroll
  for (int r = 0; r < 4; ++r)
    lsum += kAlpha * (1.f - lumP[r]) + (1.f - kAlpha) * l1v[r];
#pragma unroll
  for (int off = 32; off > 0; off >>= 1) lsum += __shfl_down(lsum, off, 64);
  if ((tid & 63) == 0) sm.red[tid >> 6] = lsum;
  __syncthreads();
  if (tid == 0) {
    float t = sm.red[0] + sm.red[1] + sm.red[2] + sm.red[3] + sm.red[4] +
              sm.red[5] + sm.red[6] + sm.red[7];
    if (USE_WS) {
      // contention-free: one plain store per block; reducer kernel sums.
      partial[blockIdx.x + (blockIdx.y << 4) + (blockIdx.z << 7)] = t;
    } else {
      atomicAdd(out, t * (20.f / (16.f * 512.f * 512.f)));
    }
  }
}

__global__ __launch_bounds__(256) void msssim_reduce_kernel(
    const float* __restrict__ partial, float* __restrict__ out) {
  const int tid = threadIdx.x;
  float s = 0.f;
#pragma unroll
  for (int i = 0; i < 8; ++i) s += partial[tid + (i << 8)];
#pragma unroll
  for (int off = 32; off > 0; off >>= 1) s += __shfl_xor(s, off, 64);
  __shared__ float red[4];
  if ((tid & 63) == 0) red[tid >> 6] = s;
  __syncthreads();
  if (tid == 0)
    out[0] =
        (red[0] + red[1] + red[2] + red[3]) * (20.f / (16.f * 512.f * 512.f));
}

}  // namespace

extern "C" void kernel_launch(void* const* d_in, const int* in_sizes, int n_in,
                              void* d_out, int out_size, void* d_ws,
                              size_t ws_size, hipStream_t stream) {
  (void)in_sizes;
  (void)n_in;
  (void)out_size;
  const float* x = (const float*)d_in[0];
  const float* y = (const float*)d_in[1];
  const float* gm = (const float*)d_in[2];
  float* out = (float*)d_out;
  dim3 grid(16, 8, 16);
  if (d_ws != nullptr && ws_size >= 2048 * sizeof(float)) {
    float* partial = (float*)d_ws;
    msssim_l1_kernel<true>
        <<<grid, dim3(512), 0, stream>>>(x, y, gm, partial, out);
    msssim_reduce_kernel<<<1, dim3(256), 0, stream>>>(partial, out);
  } else {
    hipMemsetAsync(out, 0, sizeof(float), stream);
    msssim_l1_kernel<false>
        <<<grid, dim3(512), 0, stream>>>(x, y, gm, nullptr, out);
  }
}